// Round 5
// baseline (214.821 us; speedup 1.0000x reference)
//
#include <hip/hip_runtime.h>
#include <stdint.h>

typedef __bf16 bf16x8 __attribute__((ext_vector_type(8)));
typedef float f32x4 __attribute__((ext_vector_type(4)));
typedef float f32x16 __attribute__((ext_vector_type(16)));
typedef unsigned u32x2 __attribute__((ext_vector_type(2)));
typedef unsigned u32x4 __attribute__((ext_vector_type(4)));

#define LOG2E 1.44269504088896340736f
#define ATT_SCALE 0.125f
#define CL (ATT_SCALE * LOG2E)
#define SWZ(row, colb) ((colb) ^ (((row) & 7) << 4))

#define GLOAD_LDS16(gp, lp)                                                  \
  __builtin_amdgcn_global_load_lds(                                          \
      (const __attribute__((address_space(1))) void*)(gp),                   \
      (__attribute__((address_space(3))) void*)(lp), 16, 0, 0)

__device__ __forceinline__ unsigned short f2bf(float f) {
  unsigned int x = __float_as_uint(f);
  x += 0x7fffu + ((x >> 16) & 1u);
  return (unsigned short)(x >> 16);
}

__device__ __forceinline__ float fexp2(float x) {
#if __has_builtin(__builtin_amdgcn_exp2f)
  return __builtin_amdgcn_exp2f(x);
#else
  return exp2f(x);
#endif
}

__device__ __forceinline__ unsigned cvtpk(float lo, float hi) {
  unsigned r;
  asm("v_cvt_pk_bf16_f32 %0, %1, %2" : "=v"(r) : "v"(lo), "v"(hi));
  return r;
}

__device__ __forceinline__ u32x2 plswap(unsigned a, unsigned b) {
#if __has_builtin(__builtin_amdgcn_permlane32_swap)
  return __builtin_amdgcn_permlane32_swap(a, b, false, false);
#else
  unsigned ax = (unsigned)__shfl_xor((int)a, 32);
  unsigned bx = (unsigned)__shfl_xor((int)b, 32);
  int hi = (threadIdx.x & 32) ? 1 : 0;
  u32x2 r;
  r[0] = hi ? bx : a;
  r[1] = hi ? b : ax;
  return r;
#endif
}

// ---------------- all 4 weight converts in one dispatch ----------------
__global__ __launch_bounds__(256) void cvt_weights(
    const float* __restrict__ w0, const float* __restrict__ w1,
    const float* __restrict__ w2, const float* __restrict__ w3,
    unsigned short* __restrict__ o0, unsigned short* __restrict__ o1,
    unsigned short* __restrict__ o2, unsigned short* __restrict__ o3) {
  int sel = blockIdx.x >> 10;
  const float* in = sel == 0 ? w0 : sel == 1 ? w1 : sel == 2 ? w2 : w3;
  unsigned short* out = sel == 0 ? o0 : sel == 1 ? o1 : sel == 2 ? o2 : o3;
  float scale = sel == 0 ? CL : 1.0f;   // fold softmax scale*log2e into Wq
  int i = ((blockIdx.x & 1023) * 256 + threadIdx.x) * 4;
  float4 v = *(const float4*)(in + i);
  ushort4 o;
  o.x = f2bf(v.x * scale); o.y = f2bf(v.y * scale);
  o.z = f2bf(v.z * scale); o.w = f2bf(v.w * scale);
  *(ushort4*)(out + i) = o;
}

// ---------------- [B][C][T] f32 -> [B][T][C] bf16 transpose (x and c) --------
__global__ __launch_bounds__(256) void transpose_cvt2(const float* __restrict__ x,
                                                      const float* __restrict__ c,
                                                      unsigned short* __restrict__ xT,
                                                      unsigned short* __restrict__ cT) {
  __shared__ unsigned short tile[32][33];
  const int C = 1024, T = 2048;
  int z = blockIdx.z;
  const float* in = (z < 4) ? x : c;
  unsigned short* out = (z < 4) ? xT : cT;
  int b = z & 3;
  int t0 = blockIdx.x * 32, c0 = blockIdx.y * 32;
  int tx = threadIdx.x & 31, ty = threadIdx.x >> 5;
  const float* src = in + ((size_t)b * C + c0) * T + t0;
  #pragma unroll
  for (int i = 0; i < 4; ++i) {
    int cc = ty + i * 8;
    tile[cc][tx] = f2bf(src[(size_t)cc * T + tx]);
  }
  __syncthreads();
  unsigned short* dst = out + ((size_t)b * T + t0) * C + c0;
  #pragma unroll
  for (int i = 0; i < 4; ++i) {
    int tt = ty + i * 8;
    dst[(size_t)tt * C + tx] = tile[tx][tt];
  }
}

// ---------------- fused QKV GEMM: 256x256x64 tile, 8 waves, phase-split ------
// op0: QT[t][o] = xT[t][c]*Wq'[o][c] (+bq*CL) ; op1: KT = cT*Wk + bk ;
// op2: Vb[o][t] = Wv[o][c]*cT[t][c] + bv. grid 384 x 512thr, XCD-chunked.
__global__ __launch_bounds__(512, 2) void qkv_gemm8(
    const unsigned short* __restrict__ xT, const unsigned short* __restrict__ cT,
    const unsigned short* __restrict__ wq, const unsigned short* __restrict__ wk,
    const unsigned short* __restrict__ wv,
    const float* __restrict__ bq, const float* __restrict__ bk,
    const float* __restrict__ bv,
    unsigned short* __restrict__ QT, unsigned short* __restrict__ KT,
    unsigned short* __restrict__ Vb) {
  __shared__ __align__(16) char lds[131072];   // 2 x (As 32K | Bs 32K)
  const size_t sBT = (size_t)2048 * 1024;

  const int bid = blockIdx.x;
  const int id = (bid & 7) * 48 + (bid >> 3);   // XCD-chunked, 384 % 8 == 0
  const int op = id >> 7;
  const int r = id & 127;
  const int z = r >> 5, tt = r & 31;

  const unsigned short *A, *Bw;
  unsigned short* Cp;
  const float* bias;
  int m0, n0, ldC, bias_is_m;
  float bs;
  if (op == 2) {
    m0 = (tt & 3) * 256; n0 = (tt >> 2) * 256;
    A = wv; Bw = cT + z * sBT; Cp = Vb + z * (size_t)1024 * 2048;
    bias = bv; ldC = 2048; bias_is_m = 1; bs = 1.0f;
  } else {
    m0 = (tt >> 2) * 256; n0 = (tt & 3) * 256;
    A = (op == 0 ? xT : cT) + z * sBT;
    Bw = (op == 0 ? wq : wk);
    Cp = (op == 0 ? QT : KT) + z * sBT;
    bias = (op == 0 ? bq : bk); ldC = 1024; bias_is_m = 0;
    bs = (op == 0) ? CL : 1.0f;
  }

  const int tid = threadIdx.x;
  const int l = tid & 63, w = tid >> 6;
  const int g = l >> 4, j = l & 15;
  const int wr = w >> 2, wc = w & 3;            // 2 x 4 wave grid
  const int srow = tid >> 3, sslot = tid & 7;   // 64 rows x 8 slots per chunk

  // per-thread global staging pointers: 4 chunks of 64 rows per operand
  const unsigned short* ga[4];
  const unsigned short* gb[4];
  #pragma unroll
  for (int c2 = 0; c2 < 4; ++c2) {
    int ra = m0 + c2 * 64 + srow;
    ga[c2] = A + (size_t)ra * 1024 + (sslot ^ (ra & 7)) * 8;
    int rb = n0 + c2 * 64 + srow;
    gb[c2] = Bw + (size_t)rb * 1024 + (sslot ^ (rb & 7)) * 8;
  }

  f32x4 acc[8][4] = {};

  // prologue: stage K-tile 0 into buf 0
  {
    char* As = lds;
    char* Bs = lds + 32768;
    #pragma unroll
    for (int c2 = 0; c2 < 4; ++c2) {
      GLOAD_LDS16(ga[c2], As + c2 * 8192 + tid * 16);
      GLOAD_LDS16(gb[c2], Bs + c2 * 8192 + tid * 16);
      ga[c2] += 64; gb[c2] += 64;
    }
  }
  asm volatile("s_waitcnt vmcnt(0)" ::: "memory");
  __builtin_amdgcn_s_barrier();

  for (int kt = 0; kt < 16; ++kt) {
    char* As = lds + (kt & 1) * 65536;
    char* Bs = As + 32768;
    char* An = lds + ((kt & 1) ^ 1) * 65536;
    char* Bn = An + 32768;
    const bool pf = (kt < 15);

    bf16x8 af[4][2], bfr[4][2];

    // ---- phase 0: read A mf0-3 + B nf0-1; prefetch next A ----
    #pragma unroll
    for (int mf = 0; mf < 4; ++mf) {
      int row = wr * 128 + mf * 16 + j;
      af[mf][0] = *(const bf16x8*)(As + row * 128 + SWZ(row, g * 16));
      af[mf][1] = *(const bf16x8*)(As + row * 128 + SWZ(row, 64 + g * 16));
    }
    #pragma unroll
    for (int nf = 0; nf < 2; ++nf) {
      int row = wc * 64 + nf * 16 + j;
      bfr[nf][0] = *(const bf16x8*)(Bs + row * 128 + SWZ(row, g * 16));
      bfr[nf][1] = *(const bf16x8*)(Bs + row * 128 + SWZ(row, 64 + g * 16));
    }
    if (pf) {
      #pragma unroll
      for (int c2 = 0; c2 < 4; ++c2) {
        GLOAD_LDS16(ga[c2], An + c2 * 8192 + tid * 16);
        ga[c2] += 64;
      }
    }
    __builtin_amdgcn_s_barrier();
    __builtin_amdgcn_s_setprio(1);
    #pragma unroll
    for (int mf = 0; mf < 4; ++mf)
      #pragma unroll
      for (int nf = 0; nf < 2; ++nf)
        #pragma unroll
        for (int k2 = 0; k2 < 2; ++k2)
          acc[mf][nf] = __builtin_amdgcn_mfma_f32_16x16x32_bf16(af[mf][k2], bfr[nf][k2], acc[mf][nf], 0, 0, 0);
    __builtin_amdgcn_s_setprio(0);
    __builtin_amdgcn_s_barrier();

    // ---- phase 1: read B nf2-3; prefetch next B ----
    #pragma unroll
    for (int nf = 2; nf < 4; ++nf) {
      int row = wc * 64 + nf * 16 + j;
      bfr[nf][0] = *(const bf16x8*)(Bs + row * 128 + SWZ(row, g * 16));
      bfr[nf][1] = *(const bf16x8*)(Bs + row * 128 + SWZ(row, 64 + g * 16));
    }
    if (pf) {
      #pragma unroll
      for (int c2 = 0; c2 < 4; ++c2) {
        GLOAD_LDS16(gb[c2], Bn + c2 * 8192 + tid * 16);
        gb[c2] += 64;
      }
    }
    __builtin_amdgcn_s_barrier();
    __builtin_amdgcn_s_setprio(1);
    #pragma unroll
    for (int mf = 0; mf < 4; ++mf)
      #pragma unroll
      for (int nf = 2; nf < 4; ++nf)
        #pragma unroll
        for (int k2 = 0; k2 < 2; ++k2)
          acc[mf][nf] = __builtin_amdgcn_mfma_f32_16x16x32_bf16(af[mf][k2], bfr[nf][k2], acc[mf][nf], 0, 0, 0);
    __builtin_amdgcn_s_setprio(0);
    __builtin_amdgcn_s_barrier();

    // ---- phase 2: read A mf4-7 (reuse regs) ----
    #pragma unroll
    for (int mf = 0; mf < 4; ++mf) {
      int row = wr * 128 + (mf + 4) * 16 + j;
      af[mf][0] = *(const bf16x8*)(As + row * 128 + SWZ(row, g * 16));
      af[mf][1] = *(const bf16x8*)(As + row * 128 + SWZ(row, 64 + g * 16));
    }
    __builtin_amdgcn_s_barrier();
    __builtin_amdgcn_s_setprio(1);
    #pragma unroll
    for (int mf = 0; mf < 4; ++mf)
      #pragma unroll
      for (int nf = 0; nf < 2; ++nf)
        #pragma unroll
        for (int k2 = 0; k2 < 2; ++k2)
          acc[mf + 4][nf] = __builtin_amdgcn_mfma_f32_16x16x32_bf16(af[mf][k2], bfr[nf][k2], acc[mf + 4][nf], 0, 0, 0);
    __builtin_amdgcn_s_setprio(0);
    __builtin_amdgcn_s_barrier();

    // ---- phase 3: no reads; finish quadrant; tile-boundary drain ----
    __builtin_amdgcn_s_setprio(1);
    #pragma unroll
    for (int mf = 0; mf < 4; ++mf)
      #pragma unroll
      for (int nf = 2; nf < 4; ++nf)
        #pragma unroll
        for (int k2 = 0; k2 < 2; ++k2)
          acc[mf + 4][nf] = __builtin_amdgcn_mfma_f32_16x16x32_bf16(af[mf][k2], bfr[nf][k2], acc[mf + 4][nf], 0, 0, 0);
    __builtin_amdgcn_s_setprio(0);
    asm volatile("s_waitcnt vmcnt(0)" ::: "memory");
    __builtin_amdgcn_s_barrier();
  }

  #pragma unroll
  for (int mf = 0; mf < 8; ++mf) {
    #pragma unroll
    for (int rr = 0; rr < 4; ++rr) {
      int m = m0 + wr * 128 + mf * 16 + g * 4 + rr;
      float bm = bias_is_m ? bias[m] * bs : 0.f;
      #pragma unroll
      for (int nf = 0; nf < 4; ++nf) {
        int n = n0 + wc * 64 + nf * 16 + j;
        float val = acc[mf][nf][rr] + bm + (bias_is_m ? 0.f : bias[n] * bs);
        Cp[(size_t)m * ldC + n] = f2bf(val);
      }
    }
  }
}

// ---------------- output projection GEMM: fp32 out, 2-phase pipeline --------
__global__ __launch_bounds__(256) void gemm_out(
    const unsigned short* __restrict__ Wo, const unsigned short* __restrict__ OT,
    float* __restrict__ Out, const float* __restrict__ bias) {
  __shared__ __align__(16) char lds[2][32768];
  const size_t sBT = (size_t)2048 * 1024;
  const int z = blockIdx.z;
  const int m0 = blockIdx.y * 128, n0 = blockIdx.x * 128;
  const unsigned short* A = Wo;
  const unsigned short* B = OT + z * sBT;
  float* Cp = Out + z * (size_t)1024 * 2048;

  const int tid = threadIdx.x;
  const int l = tid & 63, w = tid >> 6;
  const int g = l >> 4, j = l & 15;
  const int wr = w >> 1, wc = w & 1;
  const int srow = tid >> 3, sslot = tid & 7;

  f32x4 acc[4][4] = {};

  auto stage = [&](int bsel, int k0) {
    char* As = lds[bsel];
    char* Bs = lds[bsel] + 16384;
    #pragma unroll
    for (int p = 0; p < 4; ++p) {
      int row = p * 32 + srow;
      int ch = sslot ^ (row & 7);
      GLOAD_LDS16(A + (size_t)(m0 + row) * 1024 + k0 + ch * 8, As + (p * 256 + tid) * 16);
      GLOAD_LDS16(B + (size_t)(n0 + row) * 1024 + k0 + ch * 8, Bs + (p * 256 + tid) * 16);
    }
  };

  stage(0, 0);
  __syncthreads();

  for (int t = 0; t < 16; ++t) {
    int cur = t & 1;
    if (t < 15) stage(cur ^ 1, (t + 1) * 64);
    char* As = lds[cur];
    char* Bs = lds[cur] + 16384;
    #pragma unroll
    for (int k2 = 0; k2 < 2; ++k2) {
      bf16x8 af[4], bfr[4];
      #pragma unroll
      for (int mf = 0; mf < 4; ++mf) {
        int row = wr * 64 + mf * 16 + j;
        af[mf] = *(const bf16x8*)(As + row * 128 + SWZ(row, k2 * 64 + g * 16));
      }
      #pragma unroll
      for (int nf = 0; nf < 4; ++nf) {
        int row = wc * 64 + nf * 16 + j;
        bfr[nf] = *(const bf16x8*)(Bs + row * 128 + SWZ(row, k2 * 64 + g * 16));
      }
      #pragma unroll
      for (int mf = 0; mf < 4; ++mf)
        #pragma unroll
        for (int nf = 0; nf < 4; ++nf)
          acc[mf][nf] = __builtin_amdgcn_mfma_f32_16x16x32_bf16(af[mf], bfr[nf], acc[mf][nf], 0, 0, 0);
    }
    __syncthreads();
  }

  #pragma unroll
  for (int mf = 0; mf < 4; ++mf) {
    #pragma unroll
    for (int rr = 0; rr < 4; ++rr) {
      int m = m0 + wr * 64 + mf * 16 + g * 4 + rr;
      float bm = bias[m];
      #pragma unroll
      for (int nf = 0; nf < 4; ++nf) {
        int n = n0 + wc * 64 + nf * 16 + j;
        Cp[(size_t)m * 2048 + n] = acc[mf][nf][rr] + bm;
      }
    }
  }
}

// ---------------- flash attention v4: 2-phase double-buffered K/V -----------
__global__ __launch_bounds__(256, 3) void attn_kernel4(const unsigned short* __restrict__ QT,
                                                       const unsigned short* __restrict__ KT,
                                                       const unsigned short* __restrict__ V,
                                                       unsigned short* __restrict__ OT) {
  __shared__ __align__(16) char kv[2][16384];   // [buf][Ks 8K | Vs 8K]
  __shared__ float lbuf[4][32];

  const int fid = blockIdx.x;              // 0..1023
  const int xcd = fid & 7, idx = fid >> 3;
  const int bh = ((idx & 7) << 3) | xcd;   // 8 bh per XCD
  const int tblk = idx >> 3;               // 0..15
  const int b = bh >> 4, h = bh & 15;

  const int tid = threadIdx.x;
  const int w = tid >> 6, l = tid & 63, lo5 = l & 31, hi = l >> 5;
  const int tq0 = tblk * 128 + w * 32;

  bf16x8 q[4];
  {
    const unsigned short* Qb = QT + ((size_t)(b * 2048 + tq0 + lo5)) * 1024 + h * 64 + hi * 8;
    #pragma unroll
    for (int kb = 0; kb < 4; ++kb) q[kb] = *(const bf16x8*)(Qb + kb * 16);
  }

  f32x16 o[2] = {};
  float lr = 0.f;

  const int srow0 = tid >> 3, sslot = tid & 7;
  const unsigned short* Kg0 = KT + ((size_t)b * 2048) * 1024 + h * 64;
  const unsigned short* Vg0 = V + ((size_t)(b * 1024 + h * 64)) * 2048;

  auto stage = [&](int bsel, int s0) {
    char* Ks = kv[bsel];
    char* Vs = kv[bsel] + 8192;
    #pragma unroll
    for (int p = 0; p < 2; ++p) {
      int row = p * 32 + srow0;
      int ch = sslot ^ (row & 7);
      GLOAD_LDS16(Kg0 + (size_t)(s0 + row) * 1024 + ch * 8, Ks + (p * 256 + tid) * 16);
      GLOAD_LDS16(Vg0 + (size_t)row * 2048 + s0 + ch * 8, Vs + (p * 256 + tid) * 16);
    }
  };

  stage(0, 0);
  __syncthreads();

  for (int t = 0; t < 32; ++t) {
    int cur = t & 1;
    if (t < 31) stage(cur ^ 1, (t + 1) * 64);
    char* Ks = kv[cur];
    char* Vs = kv[cur] + 8192;

    f32x16 p0 = {}, p1 = {};
    #pragma unroll
    for (int kb = 0; kb < 4; ++kb) {
      int r0 = lo5, r1 = 32 + lo5;
      bf16x8 ka0 = *(const bf16x8*)(Ks + r0 * 128 + SWZ(r0, kb * 32 + hi * 16));
      bf16x8 ka1 = *(const bf16x8*)(Ks + r1 * 128 + SWZ(r1, kb * 32 + hi * 16));
      p0 = __builtin_amdgcn_mfma_f32_32x32x16_bf16(ka0, q[kb], p0, 0, 0, 0);
      p1 = __builtin_amdgcn_mfma_f32_32x32x16_bf16(ka1, q[kb], p1, 0, 0, 0);
    }

    float ls0 = 0.f, ls1 = 0.f, ls2 = 0.f, ls3 = 0.f;
    #pragma unroll
    for (int r = 0; r < 16; r += 4) {
      float e0 = fexp2(p0[r]), e1 = fexp2(p0[r + 1]), e2 = fexp2(p0[r + 2]), e3 = fexp2(p0[r + 3]);
      p0[r] = e0; p0[r + 1] = e1; p0[r + 2] = e2; p0[r + 3] = e3;
      ls0 += e0; ls1 += e1; ls2 += e2; ls3 += e3;
    }
    #pragma unroll
    for (int r = 0; r < 16; r += 4) {
      float e0 = fexp2(p1[r]), e1 = fexp2(p1[r + 1]), e2 = fexp2(p1[r + 2]), e3 = fexp2(p1[r + 3]);
      p1[r] = e0; p1[r + 1] = e1; p1[r + 2] = e2; p1[r + 3] = e3;
      ls0 += e0; ls1 += e1; ls2 += e2; ls3 += e3;
    }
    lr += (ls0 + ls1) + (ls2 + ls3);

    u32x4 pa[4];
    {
      u32x2 ra = plswap(cvtpk(p0[0], p0[1]), cvtpk(p0[4], p0[5]));
      u32x2 rb = plswap(cvtpk(p0[2], p0[3]), cvtpk(p0[6], p0[7]));
      pa[0] = (u32x4){ra[0], rb[0], ra[1], rb[1]};
      u32x2 rc = plswap(cvtpk(p0[8], p0[9]), cvtpk(p0[12], p0[13]));
      u32x2 rd = plswap(cvtpk(p0[10], p0[11]), cvtpk(p0[14], p0[15]));
      pa[1] = (u32x4){rc[0], rd[0], rc[1], rd[1]};
      u32x2 re = plswap(cvtpk(p1[0], p1[1]), cvtpk(p1[4], p1[5]));
      u32x2 rf = plswap(cvtpk(p1[2], p1[3]), cvtpk(p1[6], p1[7]));
      pa[2] = (u32x4){re[0], rf[0], re[1], rf[1]};
      u32x2 rg = plswap(cvtpk(p1[8], p1[9]), cvtpk(p1[12], p1[13]));
      u32x2 rh = plswap(cvtpk(p1[10], p1[11]), cvtpk(p1[14], p1[15]));
      pa[3] = (u32x4){rg[0], rh[0], rg[1], rh[1]};
    }

    #pragma unroll
    for (int sb = 0; sb < 4; ++sb)
      #pragma unroll
      for (int kb2 = 0; kb2 < 2; ++kb2) {
        int row = kb2 * 32 + lo5;
        bf16x8 vb = *(const bf16x8*)(Vs + row * 128 + SWZ(row, sb * 32 + hi * 16));
        o[kb2] = __builtin_amdgcn_mfma_f32_32x32x16_bf16(
            __builtin_bit_cast(bf16x8, pa[sb]), vb, o[kb2], 0, 0, 0);
      }
    __syncthreads();
  }

  u32x2 sw = plswap(__float_as_uint(lr), __float_as_uint(lr));
  float lt = __uint_as_float(sw[0]) + __uint_as_float(sw[1]);
  if (hi == 0) lbuf[w][lo5] = 1.0f / lt;
  unsigned short* Ob = OT + ((size_t)(b * 2048 + tq0)) * 1024 + h * 64 + lo5;
  #pragma unroll
  for (int r = 0; r < 16; ++r) {
    int srow = (r & 3) + 8 * (r >> 2) + 4 * hi;
    float inv = lbuf[w][srow];
    Ob[(size_t)srow * 1024 + 0]  = f2bf(o[0][r] * inv);
    Ob[(size_t)srow * 1024 + 32] = f2bf(o[1][r] * inv);
  }
}

// ---------------- launch ----------------
extern "C" void kernel_launch(void* const* d_in, const int* in_sizes, int n_in,
                              void* d_out, int out_size, void* d_ws, size_t ws_size,
                              hipStream_t stream) {
  const float* x  = (const float*)d_in[0];
  const float* c  = (const float*)d_in[1];
  const float* Wq = (const float*)d_in[2];
  const float* bq = (const float*)d_in[3];
  const float* Wk = (const float*)d_in[4];
  const float* bk = (const float*)d_in[5];
  const float* Wv = (const float*)d_in[6];
  const float* bv = (const float*)d_in[7];
  const float* Wo = (const float*)d_in[8];
  const float* bo = (const float*)d_in[9];

  const size_t MB = 1024 * 1024;
  char* ws = (char*)d_ws;
  unsigned short* wqb = (unsigned short*)(ws + 0 * MB);
  unsigned short* wkb = (unsigned short*)(ws + 2 * MB);
  unsigned short* wvb = (unsigned short*)(ws + 4 * MB);
  unsigned short* wob = (unsigned short*)(ws + 6 * MB);
  unsigned short* xT  = (unsigned short*)(ws + 8 * MB);   // [B][T][C] bf16, 16MB
  unsigned short* cT  = (unsigned short*)(ws + 24 * MB);
  unsigned short* QT  = (unsigned short*)(ws + 40 * MB);
  unsigned short* KT  = (unsigned short*)(ws + 56 * MB);
  unsigned short* Vb  = (unsigned short*)(ws + 72 * MB);  // [B][C][T] bf16
  unsigned short* OT  = xT;  // reuse: x dead after QKV gemm

  cvt_weights<<<dim3(4096), 256, 0, stream>>>(Wq, Wk, Wv, Wo, wqb, wkb, wvb, wob);
  transpose_cvt2<<<dim3(64, 32, 8), 256, 0, stream>>>(x, c, xT, cT);

  qkv_gemm8<<<dim3(384), 512, 0, stream>>>(xT, cT, wqb, wkb, wvb, bq, bk, bv, QT, KT, Vb);

  attn_kernel4<<<dim3(1024), 256, 0, stream>>>(QT, KT, Vb, OT);

  gemm_out<<<dim3(16, 8, 4), 256, 0, stream>>>(wob, OT, (float*)d_out, bo);
}

// Round 6
// 196.232 us; speedup vs baseline: 1.0947x; 1.0947x over previous
//
#include <hip/hip_runtime.h>
#include <stdint.h>

typedef __bf16 bf16x8 __attribute__((ext_vector_type(8)));
typedef float f32x4 __attribute__((ext_vector_type(4)));
typedef float f32x16 __attribute__((ext_vector_type(16)));
typedef unsigned u32x2 __attribute__((ext_vector_type(2)));
typedef unsigned u32x4 __attribute__((ext_vector_type(4)));

#define LOG2E 1.44269504088896340736f
#define ATT_SCALE 0.125f
#define CL (ATT_SCALE * LOG2E)
#define SWZ(row, colb) ((colb) ^ (((row) & 7) << 4))

#define GLOAD_LDS16(gp, lp)                                                  \
  __builtin_amdgcn_global_load_lds(                                          \
      (const __attribute__((address_space(1))) void*)(gp),                   \
      (__attribute__((address_space(3))) void*)(lp), 16, 0, 0)

__device__ __forceinline__ unsigned short f2bf(float f) {
  unsigned int x = __float_as_uint(f);
  x += 0x7fffu + ((x >> 16) & 1u);
  return (unsigned short)(x >> 16);
}

__device__ __forceinline__ float fexp2(float x) {
#if __has_builtin(__builtin_amdgcn_exp2f)
  return __builtin_amdgcn_exp2f(x);
#else
  return exp2f(x);
#endif
}

__device__ __forceinline__ unsigned cvtpk(float lo, float hi) {
  unsigned r;
  asm("v_cvt_pk_bf16_f32 %0, %1, %2" : "=v"(r) : "v"(lo), "v"(hi));
  return r;
}

__device__ __forceinline__ u32x2 plswap(unsigned a, unsigned b) {
#if __has_builtin(__builtin_amdgcn_permlane32_swap)
  return __builtin_amdgcn_permlane32_swap(a, b, false, false);
#else
  unsigned ax = (unsigned)__shfl_xor((int)a, 32);
  unsigned bx = (unsigned)__shfl_xor((int)b, 32);
  int hi = (threadIdx.x & 32) ? 1 : 0;
  u32x2 r;
  r[0] = hi ? bx : a;
  r[1] = hi ? b : ax;
  return r;
#endif
}

// ---------------- all 4 weight converts in one dispatch ----------------
__global__ __launch_bounds__(256) void cvt_weights(
    const float* __restrict__ w0, const float* __restrict__ w1,
    const float* __restrict__ w2, const float* __restrict__ w3,
    unsigned short* __restrict__ o0, unsigned short* __restrict__ o1,
    unsigned short* __restrict__ o2, unsigned short* __restrict__ o3) {
  int sel = blockIdx.x >> 10;
  const float* in = sel == 0 ? w0 : sel == 1 ? w1 : sel == 2 ? w2 : w3;
  unsigned short* out = sel == 0 ? o0 : sel == 1 ? o1 : sel == 2 ? o2 : o3;
  float scale = sel == 0 ? CL : 1.0f;   // fold softmax scale*log2e into Wq
  int i = ((blockIdx.x & 1023) * 256 + threadIdx.x) * 4;
  float4 v = *(const float4*)(in + i);
  ushort4 o;
  o.x = f2bf(v.x * scale); o.y = f2bf(v.y * scale);
  o.z = f2bf(v.z * scale); o.w = f2bf(v.w * scale);
  *(ushort4*)(out + i) = o;
}

// ---------------- [B][C][T] f32 -> [B][T][C] bf16 transpose (x and c) --------
__global__ __launch_bounds__(256) void transpose_cvt2(const float* __restrict__ x,
                                                      const float* __restrict__ c,
                                                      unsigned short* __restrict__ xT,
                                                      unsigned short* __restrict__ cT) {
  __shared__ unsigned short tile[32][33];
  const int C = 1024, T = 2048;
  int z = blockIdx.z;
  const float* in = (z < 4) ? x : c;
  unsigned short* out = (z < 4) ? xT : cT;
  int b = z & 3;
  int t0 = blockIdx.x * 32, c0 = blockIdx.y * 32;
  int tx = threadIdx.x & 31, ty = threadIdx.x >> 5;
  const float* src = in + ((size_t)b * C + c0) * T + t0;
  #pragma unroll
  for (int i = 0; i < 4; ++i) {
    int cc = ty + i * 8;
    tile[cc][tx] = f2bf(src[(size_t)cc * T + tx]);
  }
  __syncthreads();
  unsigned short* dst = out + ((size_t)b * T + t0) * C + c0;
  #pragma unroll
  for (int i = 0; i < 4; ++i) {
    int tt = ty + i * 8;
    dst[(size_t)tt * C + tx] = tile[tx][tt];
  }
}

// ============ 128x128 NT GEMM core, BK=32, TRIPLE-buffered, counted vmcnt ====
// A,B: bf16 rows of ld 1024. Per K-tile: vmcnt(4); barrier; issue t+2; ds_read;
// 16 MFMA. Loads span 2 full tiles; never drained in main loop (T4).
// LDS per buf 16KB (A 8K | B 8K), paired-row layout [64][64] w/ row&7 XOR swz.
template <int NT, int OUT_F32>
__device__ __forceinline__ void gemm_core128(
    const unsigned short* __restrict__ A, const unsigned short* __restrict__ B,
    void* __restrict__ Cv, const float* __restrict__ bias, int bias_is_m,
    float bs, int m0, int n0, int ldC) {
  __shared__ __align__(16) char lds[3 * 16384];
  const int tid = threadIdx.x;
  const int l = tid & 63, w = tid >> 6;
  const int g = l >> 4, j = l & 15;
  const int wr = w >> 1, wc = w & 1;

  // staging coords: dest byte p*4096 + tid*16 -> row' = p*32 + (tid>>3), slot = tid&7
  const int r0 = tid >> 3;
  const int slotp = (tid & 7) ^ (r0 & 7);          // logical slot at this dest
  const int mloc = r0 * 2 + (slotp >> 2);          // logical row within 64-half
  const int kg = slotp & 3;                        // 8-elem k-group
  const unsigned short* ga0 = A + (size_t)(m0 + mloc) * 1024 + kg * 8;
  const unsigned short* ga1 = A + (size_t)(m0 + 64 + mloc) * 1024 + kg * 8;
  const unsigned short* gb0 = B + (size_t)(n0 + mloc) * 1024 + kg * 8;
  const unsigned short* gb1 = B + (size_t)(n0 + 64 + mloc) * 1024 + kg * 8;

  auto stage = [&](char* buf) {
    GLOAD_LDS16(ga0, buf + tid * 16);
    GLOAD_LDS16(ga1, buf + 4096 + tid * 16);
    GLOAD_LDS16(gb0, buf + 8192 + tid * 16);
    GLOAD_LDS16(gb1, buf + 12288 + tid * 16);
    ga0 += 32; ga1 += 32; gb0 += 32; gb1 += 32;    // advance one K-tile (32 elems)
  };

  f32x4 acc[4][4] = {};

  stage(lds);               // tile 0 -> buf0
  stage(lds + 16384);       // tile 1 -> buf1

  char* bufc = lds;                 // compute buffer (tile t)
  char* bufs = lds + 2 * 16384;     // stage target (tile t+2)

  for (int t = 0; t < NT; ++t) {
    if (t == NT - 1) asm volatile("s_waitcnt vmcnt(0)" ::: "memory");
    else             asm volatile("s_waitcnt vmcnt(4)" ::: "memory");
    __builtin_amdgcn_s_barrier();
    asm volatile("" ::: "memory");   // compiler fence: no ds_read hoist above barrier
    if (t < NT - 2) stage(bufs);

    bf16x8 af[4], bfr[4];
    #pragma unroll
    for (int mf = 0; mf < 4; ++mf) {
      int m = wr * 64 + mf * 16 + j;
      int rp = m >> 1;
      int cb = ((m & 1) * 64 + g * 16) ^ ((rp & 7) << 4);
      af[mf] = *(const bf16x8*)(bufc + rp * 128 + cb);
    }
    #pragma unroll
    for (int nf = 0; nf < 4; ++nf) {
      int n = wc * 64 + nf * 16 + j;
      int rp = n >> 1;
      int cb = ((n & 1) * 64 + g * 16) ^ ((rp & 7) << 4);
      bfr[nf] = *(const bf16x8*)(bufc + 8192 + rp * 128 + cb);
    }
    #pragma unroll
    for (int mf = 0; mf < 4; ++mf)
      #pragma unroll
      for (int nf = 0; nf < 4; ++nf)
        acc[mf][nf] = __builtin_amdgcn_mfma_f32_16x16x32_bf16(af[mf], bfr[nf], acc[mf][nf], 0, 0, 0);

    bufc += 16384; if (bufc == lds + 49152) bufc = lds;
    bufs += 16384; if (bufs == lds + 49152) bufs = lds;
  }

  #pragma unroll
  for (int mf = 0; mf < 4; ++mf) {
    #pragma unroll
    for (int rr = 0; rr < 4; ++rr) {
      int m = m0 + wr * 64 + mf * 16 + g * 4 + rr;
      float bm = bias_is_m ? bias[m] * bs : 0.f;
      #pragma unroll
      for (int nf = 0; nf < 4; ++nf) {
        int n = n0 + wc * 64 + nf * 16 + j;
        float val = acc[mf][nf][rr] + bm + (bias_is_m ? 0.f : bias[n] * bs);
        if (OUT_F32) ((float*)Cv)[(size_t)m * ldC + n] = val;
        else ((unsigned short*)Cv)[(size_t)m * ldC + n] = f2bf(val);
      }
    }
  }
}

// ---------------- fused QKV GEMM: grid 1536 (XCD-chunked), 256 thr -----------
__global__ __launch_bounds__(256, 3) void qkv_gemm3(
    const unsigned short* __restrict__ xT, const unsigned short* __restrict__ cT,
    const unsigned short* __restrict__ wq, const unsigned short* __restrict__ wk,
    const unsigned short* __restrict__ wv,
    const float* __restrict__ bq, const float* __restrict__ bk,
    const float* __restrict__ bv,
    unsigned short* __restrict__ QT, unsigned short* __restrict__ KT,
    unsigned short* __restrict__ Vb) {
  const size_t sBT = (size_t)2048 * 1024;
  const int id = (blockIdx.x & 7) * 192 + (blockIdx.x >> 3);  // XCD chunking
  const int op = id >> 9;
  const int r = id & 511;
  const int z = r >> 7;
  const unsigned short *A, *B;
  unsigned short* Cp;
  const float* bias;
  int m0, n0, ldC, bias_is_m;
  float bs;
  if (op == 2) {
    n0 = (r & 15) * 128; m0 = ((r >> 4) & 7) * 128;
    A = wv; B = cT + z * sBT; Cp = Vb + z * (size_t)1024 * 2048;
    bias = bv; ldC = 2048; bias_is_m = 1; bs = 1.0f;
  } else {
    n0 = (r & 7) * 128; m0 = ((r >> 3) & 15) * 128;
    A = (op == 0 ? xT : cT) + z * sBT;
    B = (op == 0 ? wq : wk);
    Cp = (op == 0 ? QT : KT) + z * sBT;
    bias = (op == 0 ? bq : bk); ldC = 1024; bias_is_m = 0;
    bs = (op == 0) ? CL : 1.0f;
  }
  gemm_core128<32, 0>(A, B, Cp, bias, bias_is_m, bs, m0, n0, ldC);
}

// ---------------- output projection: grid 512 (XCD-chunked), fp32 out --------
__global__ __launch_bounds__(256, 3) void gemm_out3(
    const unsigned short* __restrict__ Wo, const unsigned short* __restrict__ OT,
    float* __restrict__ Out, const float* __restrict__ bias) {
  const size_t sBT = (size_t)2048 * 1024;
  const int id = (blockIdx.x & 7) * 64 + (blockIdx.x >> 3);
  const int z = id >> 7;
  const int m0 = ((id >> 4) & 7) * 128, n0 = (id & 15) * 128;
  gemm_core128<32, 1>(Wo, OT + z * sBT, Out + z * (size_t)1024 * 2048,
                      bias, 1, 1.0f, m0, n0, 2048);
}

// ---------------- flash attention v4: 2-phase double-buffered K/V -----------
__global__ __launch_bounds__(256, 3) void attn_kernel4(const unsigned short* __restrict__ QT,
                                                       const unsigned short* __restrict__ KT,
                                                       const unsigned short* __restrict__ V,
                                                       unsigned short* __restrict__ OT) {
  __shared__ __align__(16) char kv[2][16384];   // [buf][Ks 8K | Vs 8K]
  __shared__ float lbuf[4][32];

  const int fid = blockIdx.x;              // 0..1023
  const int xcd = fid & 7, idx = fid >> 3;
  const int bh = ((idx & 7) << 3) | xcd;   // 8 bh per XCD
  const int tblk = idx >> 3;               // 0..15
  const int b = bh >> 4, h = bh & 15;

  const int tid = threadIdx.x;
  const int w = tid >> 6, l = tid & 63, lo5 = l & 31, hi = l >> 5;
  const int tq0 = tblk * 128 + w * 32;

  bf16x8 q[4];
  {
    const unsigned short* Qb = QT + ((size_t)(b * 2048 + tq0 + lo5)) * 1024 + h * 64 + hi * 8;
    #pragma unroll
    for (int kb = 0; kb < 4; ++kb) q[kb] = *(const bf16x8*)(Qb + kb * 16);
  }

  f32x16 o[2] = {};
  float lr = 0.f;

  const int srow0 = tid >> 3, sslot = tid & 7;
  const unsigned short* Kg0 = KT + ((size_t)b * 2048) * 1024 + h * 64;
  const unsigned short* Vg0 = V + ((size_t)(b * 1024 + h * 64)) * 2048;

  auto stage = [&](int bsel, int s0) {
    char* Ks = kv[bsel];
    char* Vs = kv[bsel] + 8192;
    #pragma unroll
    for (int p = 0; p < 2; ++p) {
      int row = p * 32 + srow0;
      int ch = sslot ^ (row & 7);
      GLOAD_LDS16(Kg0 + (size_t)(s0 + row) * 1024 + ch * 8, Ks + (p * 256 + tid) * 16);
      GLOAD_LDS16(Vg0 + (size_t)row * 2048 + s0 + ch * 8, Vs + (p * 256 + tid) * 16);
    }
  };

  stage(0, 0);
  __syncthreads();

  for (int t = 0; t < 32; ++t) {
    int cur = t & 1;
    if (t < 31) stage(cur ^ 1, (t + 1) * 64);
    char* Ks = kv[cur];
    char* Vs = kv[cur] + 8192;

    f32x16 p0 = {}, p1 = {};
    #pragma unroll
    for (int kb = 0; kb < 4; ++kb) {
      int r0 = lo5, r1 = 32 + lo5;
      bf16x8 ka0 = *(const bf16x8*)(Ks + r0 * 128 + SWZ(r0, kb * 32 + hi * 16));
      bf16x8 ka1 = *(const bf16x8*)(Ks + r1 * 128 + SWZ(r1, kb * 32 + hi * 16));
      p0 = __builtin_amdgcn_mfma_f32_32x32x16_bf16(ka0, q[kb], p0, 0, 0, 0);
      p1 = __builtin_amdgcn_mfma_f32_32x32x16_bf16(ka1, q[kb], p1, 0, 0, 0);
    }

    float ls0 = 0.f, ls1 = 0.f, ls2 = 0.f, ls3 = 0.f;
    #pragma unroll
    for (int r = 0; r < 16; r += 4) {
      float e0 = fexp2(p0[r]), e1 = fexp2(p0[r + 1]), e2 = fexp2(p0[r + 2]), e3 = fexp2(p0[r + 3]);
      p0[r] = e0; p0[r + 1] = e1; p0[r + 2] = e2; p0[r + 3] = e3;
      ls0 += e0; ls1 += e1; ls2 += e2; ls3 += e3;
    }
    #pragma unroll
    for (int r = 0; r < 16; r += 4) {
      float e0 = fexp2(p1[r]), e1 = fexp2(p1[r + 1]), e2 = fexp2(p1[r + 2]), e3 = fexp2(p1[r + 3]);
      p1[r] = e0; p1[r + 1] = e1; p1[r + 2] = e2; p1[r + 3] = e3;
      ls0 += e0; ls1 += e1; ls2 += e2; ls3 += e3;
    }
    lr += (ls0 + ls1) + (ls2 + ls3);

    u32x4 pa[4];
    {
      u32x2 ra = plswap(cvtpk(p0[0], p0[1]), cvtpk(p0[4], p0[5]));
      u32x2 rb = plswap(cvtpk(p0[2], p0[3]), cvtpk(p0[6], p0[7]));
      pa[0] = (u32x4){ra[0], rb[0], ra[1], rb[1]};
      u32x2 rc = plswap(cvtpk(p0[8], p0[9]), cvtpk(p0[12], p0[13]));
      u32x2 rd = plswap(cvtpk(p0[10], p0[11]), cvtpk(p0[14], p0[15]));
      pa[1] = (u32x4){rc[0], rd[0], rc[1], rd[1]};
      u32x2 re = plswap(cvtpk(p1[0], p1[1]), cvtpk(p1[4], p1[5]));
      u32x2 rf = plswap(cvtpk(p1[2], p1[3]), cvtpk(p1[6], p1[7]));
      pa[2] = (u32x4){re[0], rf[0], re[1], rf[1]};
      u32x2 rg = plswap(cvtpk(p1[8], p1[9]), cvtpk(p1[12], p1[13]));
      u32x2 rh = plswap(cvtpk(p1[10], p1[11]), cvtpk(p1[14], p1[15]));
      pa[3] = (u32x4){rg[0], rh[0], rg[1], rh[1]};
    }

    #pragma unroll
    for (int sb = 0; sb < 4; ++sb)
      #pragma unroll
      for (int kb2 = 0; kb2 < 2; ++kb2) {
        int row = kb2 * 32 + lo5;
        bf16x8 vb = *(const bf16x8*)(Vs + row * 128 + SWZ(row, sb * 32 + hi * 16));
        o[kb2] = __builtin_amdgcn_mfma_f32_32x32x16_bf16(
            __builtin_bit_cast(bf16x8, pa[sb]), vb, o[kb2], 0, 0, 0);
      }
    __syncthreads();
  }

  u32x2 sw = plswap(__float_as_uint(lr), __float_as_uint(lr));
  float lt = __uint_as_float(sw[0]) + __uint_as_float(sw[1]);
  if (hi == 0) lbuf[w][lo5] = 1.0f / lt;
  unsigned short* Ob = OT + ((size_t)(b * 2048 + tq0)) * 1024 + h * 64 + lo5;
  #pragma unroll
  for (int r = 0; r < 16; ++r) {
    int srow = (r & 3) + 8 * (r >> 2) + 4 * hi;
    float inv = lbuf[w][srow];
    Ob[(size_t)srow * 1024 + 0]  = f2bf(o[0][r] * inv);
    Ob[(size_t)srow * 1024 + 32] = f2bf(o[1][r] * inv);
  }
}

// ---------------- launch ----------------
extern "C" void kernel_launch(void* const* d_in, const int* in_sizes, int n_in,
                              void* d_out, int out_size, void* d_ws, size_t ws_size,
                              hipStream_t stream) {
  const float* x  = (const float*)d_in[0];
  const float* c  = (const float*)d_in[1];
  const float* Wq = (const float*)d_in[2];
  const float* bq = (const float*)d_in[3];
  const float* Wk = (const float*)d_in[4];
  const float* bk = (const float*)d_in[5];
  const float* Wv = (const float*)d_in[6];
  const float* bv = (const float*)d_in[7];
  const float* Wo = (const float*)d_in[8];
  const float* bo = (const float*)d_in[9];

  const size_t MB = 1024 * 1024;
  char* ws = (char*)d_ws;
  unsigned short* wqb = (unsigned short*)(ws + 0 * MB);
  unsigned short* wkb = (unsigned short*)(ws + 2 * MB);
  unsigned short* wvb = (unsigned short*)(ws + 4 * MB);
  unsigned short* wob = (unsigned short*)(ws + 6 * MB);
  unsigned short* xT  = (unsigned short*)(ws + 8 * MB);   // [B][T][C] bf16, 16MB
  unsigned short* cT  = (unsigned short*)(ws + 24 * MB);
  unsigned short* QT  = (unsigned short*)(ws + 40 * MB);
  unsigned short* KT  = (unsigned short*)(ws + 56 * MB);
  unsigned short* Vb  = (unsigned short*)(ws + 72 * MB);  // [B][C][T] bf16
  unsigned short* OT  = xT;  // reuse: x dead after QKV gemm

  cvt_weights<<<dim3(4096), 256, 0, stream>>>(Wq, Wk, Wv, Wo, wqb, wkb, wvb, wob);
  transpose_cvt2<<<dim3(64, 32, 8), 256, 0, stream>>>(x, c, xT, cT);

  qkv_gemm3<<<dim3(1536), 256, 0, stream>>>(xT, cT, wqb, wkb, wvb, bq, bk, bv, QT, KT, Vb);

  attn_kernel4<<<dim3(1024), 256, 0, stream>>>(QT, KT, Vb, OT);

  gemm_out3<<<dim3(512), 256, 0, stream>>>(wob, OT, (float*)d_out, bo);
}

// Round 7
// 189.612 us; speedup vs baseline: 1.1329x; 1.0349x over previous
//
#include <hip/hip_runtime.h>
#include <stdint.h>

typedef __bf16 bf16x8 __attribute__((ext_vector_type(8)));
typedef float f32x4 __attribute__((ext_vector_type(4)));
typedef float f32x16 __attribute__((ext_vector_type(16)));
typedef unsigned u32x2 __attribute__((ext_vector_type(2)));
typedef unsigned u32x4 __attribute__((ext_vector_type(4)));

#define LOG2E 1.44269504088896340736f
#define ATT_SCALE 0.125f
#define CL (ATT_SCALE * LOG2E)
#define SWZ(row, colb) ((colb) ^ (((row) & 7) << 4))

#define GLOAD_LDS16(gp, lp)                                                  \
  __builtin_amdgcn_global_load_lds(                                          \
      (const __attribute__((address_space(1))) void*)(gp),                   \
      (__attribute__((address_space(3))) void*)(lp), 16, 0, 0)

__device__ __forceinline__ unsigned short f2bf(float f) {
  unsigned int x = __float_as_uint(f);
  x += 0x7fffu + ((x >> 16) & 1u);
  return (unsigned short)(x >> 16);
}

__device__ __forceinline__ float fexp2(float x) {
#if __has_builtin(__builtin_amdgcn_exp2f)
  return __builtin_amdgcn_exp2f(x);
#else
  return exp2f(x);
#endif
}

__device__ __forceinline__ unsigned cvtpk(float lo, float hi) {
  unsigned r;
  asm("v_cvt_pk_bf16_f32 %0, %1, %2" : "=v"(r) : "v"(lo), "v"(hi));
  return r;
}

// HW v_permlane32_swap_b32: swaps a.hi ↔ b.lo (pure VALU, no LDS crossbar).
// result: r[0] = {lanes<32: a(own); lanes>=32: b(partner-lo)}
//         r[1] = {lanes<32: a(partner-hi); lanes>=32: b(own)}
__device__ __forceinline__ u32x2 plswap(unsigned a, unsigned b) {
  asm("v_permlane32_swap_b32 %0, %1" : "+v"(a), "+v"(b));
  u32x2 r;
  r[0] = a;
  r[1] = b;
  return r;
}

// ---------------- all 4 weight converts in one dispatch ----------------
__global__ __launch_bounds__(256) void cvt_weights(
    const float* __restrict__ w0, const float* __restrict__ w1,
    const float* __restrict__ w2, const float* __restrict__ w3,
    unsigned short* __restrict__ o0, unsigned short* __restrict__ o1,
    unsigned short* __restrict__ o2, unsigned short* __restrict__ o3) {
  int sel = blockIdx.x >> 10;
  const float* in = sel == 0 ? w0 : sel == 1 ? w1 : sel == 2 ? w2 : w3;
  unsigned short* out = sel == 0 ? o0 : sel == 1 ? o1 : sel == 2 ? o2 : o3;
  float scale = sel == 0 ? CL : 1.0f;   // fold softmax scale*log2e into Wq
  int i = ((blockIdx.x & 1023) * 256 + threadIdx.x) * 4;
  float4 v = *(const float4*)(in + i);
  ushort4 o;
  o.x = f2bf(v.x * scale); o.y = f2bf(v.y * scale);
  o.z = f2bf(v.z * scale); o.w = f2bf(v.w * scale);
  *(ushort4*)(out + i) = o;
}

// ---------------- [B][C][T] f32 -> [B][T][C] bf16 transpose (x and c) --------
__global__ __launch_bounds__(256) void transpose_cvt2(const float* __restrict__ x,
                                                      const float* __restrict__ c,
                                                      unsigned short* __restrict__ xT,
                                                      unsigned short* __restrict__ cT) {
  __shared__ unsigned short tile[32][33];
  const int C = 1024, T = 2048;
  int z = blockIdx.z;
  const float* in = (z < 4) ? x : c;
  unsigned short* out = (z < 4) ? xT : cT;
  int b = z & 3;
  int t0 = blockIdx.x * 32, c0 = blockIdx.y * 32;
  int tx = threadIdx.x & 31, ty = threadIdx.x >> 5;
  const float* src = in + ((size_t)b * C + c0) * T + t0;
  #pragma unroll
  for (int i = 0; i < 4; ++i) {
    int cc = ty + i * 8;
    tile[cc][tx] = f2bf(src[(size_t)cc * T + tx]);
  }
  __syncthreads();
  unsigned short* dst = out + ((size_t)b * T + t0) * C + c0;
  #pragma unroll
  for (int i = 0; i < 4; ++i) {
    int tt = ty + i * 8;
    dst[(size_t)tt * C + tx] = tile[tx][tt];
  }
}

// ============ 128x128 NT GEMM core, BK=32, TRIPLE-buffered, counted vmcnt ====
template <int NT, int OUT_F32>
__device__ __forceinline__ void gemm_core128(
    const unsigned short* __restrict__ A, const unsigned short* __restrict__ B,
    void* __restrict__ Cv, const float* __restrict__ bias, int bias_is_m,
    float bs, int m0, int n0, int ldC) {
  __shared__ __align__(16) char lds[3 * 16384];
  const int tid = threadIdx.x;
  const int l = tid & 63, w = tid >> 6;
  const int g = l >> 4, j = l & 15;
  const int wr = w >> 1, wc = w & 1;

  const int r0 = tid >> 3;
  const int slotp = (tid & 7) ^ (r0 & 7);
  const int mloc = r0 * 2 + (slotp >> 2);
  const int kg = slotp & 3;
  const unsigned short* ga0 = A + (size_t)(m0 + mloc) * 1024 + kg * 8;
  const unsigned short* ga1 = A + (size_t)(m0 + 64 + mloc) * 1024 + kg * 8;
  const unsigned short* gb0 = B + (size_t)(n0 + mloc) * 1024 + kg * 8;
  const unsigned short* gb1 = B + (size_t)(n0 + 64 + mloc) * 1024 + kg * 8;

  auto stage = [&](char* buf) {
    GLOAD_LDS16(ga0, buf + tid * 16);
    GLOAD_LDS16(ga1, buf + 4096 + tid * 16);
    GLOAD_LDS16(gb0, buf + 8192 + tid * 16);
    GLOAD_LDS16(gb1, buf + 12288 + tid * 16);
    ga0 += 32; ga1 += 32; gb0 += 32; gb1 += 32;
  };

  f32x4 acc[4][4] = {};

  stage(lds);
  stage(lds + 16384);

  char* bufc = lds;
  char* bufs = lds + 2 * 16384;

  for (int t = 0; t < NT; ++t) {
    if (t == NT - 1) asm volatile("s_waitcnt vmcnt(0)" ::: "memory");
    else             asm volatile("s_waitcnt vmcnt(4)" ::: "memory");
    __builtin_amdgcn_s_barrier();
    asm volatile("" ::: "memory");
    if (t < NT - 2) stage(bufs);

    bf16x8 af[4], bfr[4];
    #pragma unroll
    for (int mf = 0; mf < 4; ++mf) {
      int m = wr * 64 + mf * 16 + j;
      int rp = m >> 1;
      int cb = ((m & 1) * 64 + g * 16) ^ ((rp & 7) << 4);
      af[mf] = *(const bf16x8*)(bufc + rp * 128 + cb);
    }
    #pragma unroll
    for (int nf = 0; nf < 4; ++nf) {
      int n = wc * 64 + nf * 16 + j;
      int rp = n >> 1;
      int cb = ((n & 1) * 64 + g * 16) ^ ((rp & 7) << 4);
      bfr[nf] = *(const bf16x8*)(bufc + 8192 + rp * 128 + cb);
    }
    #pragma unroll
    for (int mf = 0; mf < 4; ++mf)
      #pragma unroll
      for (int nf = 0; nf < 4; ++nf)
        acc[mf][nf] = __builtin_amdgcn_mfma_f32_16x16x32_bf16(af[mf], bfr[nf], acc[mf][nf], 0, 0, 0);

    bufc += 16384; if (bufc == lds + 49152) bufc = lds;
    bufs += 16384; if (bufs == lds + 49152) bufs = lds;
  }

  #pragma unroll
  for (int mf = 0; mf < 4; ++mf) {
    #pragma unroll
    for (int rr = 0; rr < 4; ++rr) {
      int m = m0 + wr * 64 + mf * 16 + g * 4 + rr;
      float bm = bias_is_m ? bias[m] * bs : 0.f;
      #pragma unroll
      for (int nf = 0; nf < 4; ++nf) {
        int n = n0 + wc * 64 + nf * 16 + j;
        float val = acc[mf][nf][rr] + bm + (bias_is_m ? 0.f : bias[n] * bs);
        if (OUT_F32) ((float*)Cv)[(size_t)m * ldC + n] = val;
        else ((unsigned short*)Cv)[(size_t)m * ldC + n] = f2bf(val);
      }
    }
  }
}

// ---------------- fused QKV GEMM: grid 1536 (XCD-chunked), 256 thr -----------
__global__ __launch_bounds__(256, 3) void qkv_gemm3(
    const unsigned short* __restrict__ xT, const unsigned short* __restrict__ cT,
    const unsigned short* __restrict__ wq, const unsigned short* __restrict__ wk,
    const unsigned short* __restrict__ wv,
    const float* __restrict__ bq, const float* __restrict__ bk,
    const float* __restrict__ bv,
    unsigned short* __restrict__ QT, unsigned short* __restrict__ KT,
    unsigned short* __restrict__ Vb) {
  const size_t sBT = (size_t)2048 * 1024;
  const int id = (blockIdx.x & 7) * 192 + (blockIdx.x >> 3);  // XCD chunking
  const int op = id >> 9;
  const int r = id & 511;
  const int z = r >> 7;
  const unsigned short *A, *B;
  unsigned short* Cp;
  const float* bias;
  int m0, n0, ldC, bias_is_m;
  float bs;
  if (op == 2) {
    n0 = (r & 15) * 128; m0 = ((r >> 4) & 7) * 128;
    A = wv; B = cT + z * sBT; Cp = Vb + z * (size_t)1024 * 2048;
    bias = bv; ldC = 2048; bias_is_m = 1; bs = 1.0f;
  } else {
    n0 = (r & 7) * 128; m0 = ((r >> 3) & 15) * 128;
    A = (op == 0 ? xT : cT) + z * sBT;
    B = (op == 0 ? wq : wk);
    Cp = (op == 0 ? QT : KT) + z * sBT;
    bias = (op == 0 ? bq : bk); ldC = 1024; bias_is_m = 0;
    bs = (op == 0) ? CL : 1.0f;
  }
  gemm_core128<32, 0>(A, B, Cp, bias, bias_is_m, bs, m0, n0, ldC);
}

// ---------------- output projection: grid 512 (XCD-chunked), fp32 out --------
__global__ __launch_bounds__(256, 3) void gemm_out3(
    const unsigned short* __restrict__ Wo, const unsigned short* __restrict__ OT,
    float* __restrict__ Out, const float* __restrict__ bias) {
  const size_t sBT = (size_t)2048 * 1024;
  const int id = (blockIdx.x & 7) * 64 + (blockIdx.x >> 3);
  const int z = id >> 7;
  const int m0 = ((id >> 4) & 7) * 128, n0 = (id & 15) * 128;
  gemm_core128<32, 1>(Wo, OT + z * sBT, Out + z * (size_t)1024 * 2048,
                      bias, 1, 1.0f, m0, n0, 2048);
}

// ---------------- flash attention v5: HW permlane + ones-MFMA l-sum ---------
// QT (pre-scaled by CL), KT: [B][2048][1024] bf16; V: [B][1024][2048] bf16.
// grid 1024 (XCD-grouped), block 256 = 4 waves x 32 q-rows, 4 blocks/CU.
__global__ __launch_bounds__(256, 4) void attn_kernel5(const unsigned short* __restrict__ QT,
                                                       const unsigned short* __restrict__ KT,
                                                       const unsigned short* __restrict__ V,
                                                       unsigned short* __restrict__ OT) {
  __shared__ __align__(16) char kv[2][16384];   // [buf][Ks 8K | Vs 8K]

  const int fid = blockIdx.x;              // 0..1023
  const int xcd = fid & 7, idx = fid >> 3;
  const int bh = ((idx & 7) << 3) | xcd;   // 8 bh per XCD
  const int tblk = idx >> 3;               // 0..15
  const int b = bh >> 4, h = bh & 15;

  const int tid = threadIdx.x;
  const int w = tid >> 6, l = tid & 63, lo5 = l & 31, hi = l >> 5;
  const int tq0 = tblk * 128 + w * 32;

  bf16x8 q[4];
  {
    const unsigned short* Qb = QT + ((size_t)(b * 2048 + tq0 + lo5)) * 1024 + h * 64 + hi * 8;
    #pragma unroll
    for (int kb = 0; kb < 4; ++kb) q[kb] = *(const bf16x8*)(Qb + kb * 16);
  }

  f32x16 o[2] = {};
  f32x16 ol = {};   // row-sum accumulator via ones-MFMA: ol[r] = l[t=crow(r,hi)]

  // B-operand of all-ones: C[t][j] += sum_s P[t][s] * 1
  const unsigned one2 = 0x3F803F80u;
  const bf16x8 ones = __builtin_bit_cast(bf16x8, (u32x4){one2, one2, one2, one2});

  const int srow0 = tid >> 3, sslot = tid & 7;
  const unsigned short* Kg0 = KT + ((size_t)b * 2048) * 1024 + h * 64;
  const unsigned short* Vg0 = V + ((size_t)(b * 1024 + h * 64)) * 2048;

  auto stage = [&](int bsel, int s0) {
    char* Ks = kv[bsel];
    char* Vs = kv[bsel] + 8192;
    #pragma unroll
    for (int p = 0; p < 2; ++p) {
      int row = p * 32 + srow0;
      int ch = sslot ^ (row & 7);
      GLOAD_LDS16(Kg0 + (size_t)(s0 + row) * 1024 + ch * 8, Ks + (p * 256 + tid) * 16);
      GLOAD_LDS16(Vg0 + (size_t)row * 2048 + s0 + ch * 8, Vs + (p * 256 + tid) * 16);
    }
  };

  stage(0, 0);
  __syncthreads();

  for (int t = 0; t < 32; ++t) {
    int cur = t & 1;
    if (t < 31) stage(cur ^ 1, (t + 1) * 64);
    char* Ks = kv[cur];
    char* Vs = kv[cur] + 8192;

    // QK^T (swapped): p0 = s rows 0..31, p1 = s rows 32..63; col = lane&31 = t
    f32x16 p0 = {}, p1 = {};
    #pragma unroll
    for (int kb = 0; kb < 4; ++kb) {
      int r0 = lo5, r1 = 32 + lo5;
      bf16x8 ka0 = *(const bf16x8*)(Ks + r0 * 128 + SWZ(r0, kb * 32 + hi * 16));
      bf16x8 ka1 = *(const bf16x8*)(Ks + r1 * 128 + SWZ(r1, kb * 32 + hi * 16));
      p0 = __builtin_amdgcn_mfma_f32_32x32x16_bf16(ka0, q[kb], p0, 0, 0, 0);
      p1 = __builtin_amdgcn_mfma_f32_32x32x16_bf16(ka1, q[kb], p1, 0, 0, 0);
    }

    // softmax numerators, static m=0 (scores pre-scaled by CL at Q projection)
    #pragma unroll
    for (int r = 0; r < 16; ++r) p0[r] = fexp2(p0[r]);
    #pragma unroll
    for (int r = 0; r < 16; ++r) p1[r] = fexp2(p1[r]);

    // pack P -> bf16 A-frags via cvt_pk + v_permlane32_swap
    u32x4 pa[4];
    {
      u32x2 ra = plswap(cvtpk(p0[0], p0[1]), cvtpk(p0[4], p0[5]));
      u32x2 rb = plswap(cvtpk(p0[2], p0[3]), cvtpk(p0[6], p0[7]));
      pa[0] = (u32x4){ra[0], rb[0], ra[1], rb[1]};
      u32x2 rc = plswap(cvtpk(p0[8], p0[9]), cvtpk(p0[12], p0[13]));
      u32x2 rd = plswap(cvtpk(p0[10], p0[11]), cvtpk(p0[14], p0[15]));
      pa[1] = (u32x4){rc[0], rd[0], rc[1], rd[1]};
      u32x2 re = plswap(cvtpk(p1[0], p1[1]), cvtpk(p1[4], p1[5]));
      u32x2 rf = plswap(cvtpk(p1[2], p1[3]), cvtpk(p1[6], p1[7]));
      pa[2] = (u32x4){re[0], rf[0], re[1], rf[1]};
      u32x2 rg = plswap(cvtpk(p1[8], p1[9]), cvtpk(p1[12], p1[13]));
      u32x2 rh = plswap(cvtpk(p1[10], p1[11]), cvtpk(p1[14], p1[15]));
      pa[3] = (u32x4){rg[0], rh[0], rg[1], rh[1]};
    }

    // PV + l-sum: o[kb2] += P * V^T ; ol += P * ones
    #pragma unroll
    for (int sb = 0; sb < 4; ++sb) {
      bf16x8 pab = __builtin_bit_cast(bf16x8, pa[sb]);
      #pragma unroll
      for (int kb2 = 0; kb2 < 2; ++kb2) {
        int row = kb2 * 32 + lo5;
        bf16x8 vb = *(const bf16x8*)(Vs + row * 128 + SWZ(row, sb * 32 + hi * 16));
        o[kb2] = __builtin_amdgcn_mfma_f32_32x32x16_bf16(pab, vb, o[kb2], 0, 0, 0);
      }
      ol = __builtin_amdgcn_mfma_f32_32x32x16_bf16(pab, ones, ol, 0, 0, 0);
    }
    __syncthreads();
  }

  // epilogue: ol[r] is l for exactly the t-row this r stores -> direct 1/l
  unsigned short* Ob = OT + ((size_t)(b * 2048 + tq0)) * 1024 + h * 64 + lo5;
  #pragma unroll
  for (int r = 0; r < 16; ++r) {
    int srow = (r & 3) + 8 * (r >> 2) + 4 * hi;
    float inv = 1.0f / ol[r];
    Ob[(size_t)srow * 1024 + 0]  = f2bf(o[0][r] * inv);
    Ob[(size_t)srow * 1024 + 32] = f2bf(o[1][r] * inv);
  }
}

// ---------------- launch ----------------
extern "C" void kernel_launch(void* const* d_in, const int* in_sizes, int n_in,
                              void* d_out, int out_size, void* d_ws, size_t ws_size,
                              hipStream_t stream) {
  const float* x  = (const float*)d_in[0];
  const float* c  = (const float*)d_in[1];
  const float* Wq = (const float*)d_in[2];
  const float* bq = (const float*)d_in[3];
  const float* Wk = (const float*)d_in[4];
  const float* bk = (const float*)d_in[5];
  const float* Wv = (const float*)d_in[6];
  const float* bv = (const float*)d_in[7];
  const float* Wo = (const float*)d_in[8];
  const float* bo = (const float*)d_in[9];

  const size_t MB = 1024 * 1024;
  char* ws = (char*)d_ws;
  unsigned short* wqb = (unsigned short*)(ws + 0 * MB);
  unsigned short* wkb = (unsigned short*)(ws + 2 * MB);
  unsigned short* wvb = (unsigned short*)(ws + 4 * MB);
  unsigned short* wob = (unsigned short*)(ws + 6 * MB);
  unsigned short* xT  = (unsigned short*)(ws + 8 * MB);   // [B][T][C] bf16, 16MB
  unsigned short* cT  = (unsigned short*)(ws + 24 * MB);
  unsigned short* QT  = (unsigned short*)(ws + 40 * MB);
  unsigned short* KT  = (unsigned short*)(ws + 56 * MB);
  unsigned short* Vb  = (unsigned short*)(ws + 72 * MB);  // [B][C][T] bf16
  unsigned short* OT  = xT;  // reuse: x dead after QKV gemm

  cvt_weights<<<dim3(4096), 256, 0, stream>>>(Wq, Wk, Wv, Wo, wqb, wkb, wvb, wob);
  transpose_cvt2<<<dim3(64, 32, 8), 256, 0, stream>>>(x, c, xT, cT);

  qkv_gemm3<<<dim3(1536), 256, 0, stream>>>(xT, cT, wqb, wkb, wvb, bq, bk, bv, QT, KT, Vb);

  attn_kernel5<<<dim3(1024), 256, 0, stream>>>(QT, KT, Vb, OT);

  gemm_out3<<<dim3(512), 256, 0, stream>>>(wob, OT, (float*)d_out, bo);
}